// Round 3
// baseline (621.046 us; speedup 1.0000x reference)
//
#include <hip/hip_runtime.h>
#include <hip/hip_bf16.h>
#include <stdint.h>

typedef __attribute__((ext_vector_type(8))) short short8;
typedef __attribute__((ext_vector_type(4))) float floatx4;

#define MFMA16(a, b, c) __builtin_amdgcn_mfma_f32_16x16x32_bf16(a, b, c, 0, 0, 0)

constexpr int N_Q  = 8192;
constexpr int M_KV = 8192;
constexpr int DMID = 128;
constexpr int DV   = 256;
constexpr int MWORDS = M_KV / 64;   // 128 u64 words per mask row

__device__ __forceinline__ unsigned short f2bf(float x) {
    unsigned u = __float_as_uint(x);
    u += 0x7fffu + ((u >> 16) & 1u);
    return (unsigned short)(u >> 16);
}

__device__ __forceinline__ short8 cvt_f8_bf8(float4 a, float4 b) {
    short8 r;
    r[0] = (short)f2bf(a.x); r[1] = (short)f2bf(a.y);
    r[2] = (short)f2bf(a.z); r[3] = (short)f2bf(a.w);
    r[4] = (short)f2bf(b.x); r[5] = (short)f2bf(b.y);
    r[6] = (short)f2bf(b.z); r[7] = (short)f2bf(b.w);
    return r;
}

// ---------------------------------------------------------------------------
// Mask dtype detection: 0 = int32 {0,1}, 1 = uint8 {0,1}, 2 = float32 {0,1}
// ---------------------------------------------------------------------------
__global__ void detect_mask_kernel(const unsigned int* __restrict__ mw, int* __restrict__ flag) {
    int t = threadIdx.x;
    unsigned w = mw[t];
    bool isf = (w == 0x3f800000u);
    bool isb = (w > 1u) && !isf;
    unsigned long long bf = __ballot(isf);
    unsigned long long bb = __ballot(isb);
    if (t == 0) *flag = bf ? 2 : (bb ? 1 : 0);
}

// ---------------------------------------------------------------------------
// Pack mask -> 1 bit per element.
// ---------------------------------------------------------------------------
__global__ __launch_bounds__(256) void pack_mask_kernel(
    const void* __restrict__ mask, const int* __restrict__ flagp,
    unsigned long long* __restrict__ Mb)
{
    const int w = blockIdx.x * 256 + threadIdx.x;
    const int f = *flagp;
    unsigned long long bits = 0;
    if (f == 1) {   // uint8
        const uint4* p = (const uint4*)((const unsigned char*)mask + (size_t)w * 64);
#pragma unroll
        for (int i = 0; i < 4; ++i) {
            uint4 v = p[i];
            unsigned x[4] = {v.x, v.y, v.z, v.w};
#pragma unroll
            for (int j = 0; j < 4; ++j)
#pragma unroll
                for (int b = 0; b < 4; ++b)
                    bits |= (unsigned long long)(((x[j] >> (b * 8)) & 0xffu) != 0) << (i * 16 + j * 4 + b);
        }
    } else {        // int32 or float32 {0,1}: nonzero test on raw bits works
        const uint4* p = (const uint4*)((const unsigned int*)mask + (size_t)w * 64);
#pragma unroll
        for (int i = 0; i < 16; ++i) {
            uint4 v = p[i];
            bits |= (unsigned long long)(v.x != 0) << (i * 4 + 0);
            bits |= (unsigned long long)(v.y != 0) << (i * 4 + 1);
            bits |= (unsigned long long)(v.z != 0) << (i * 4 + 2);
            bits |= (unsigned long long)(v.w != 0) << (i * 4 + 3);
        }
    }
    Mb[w] = bits;
}

// ---------------------------------------------------------------------------
// Projections: dst[row,0:128] = src[row,0:256] @ W[128,256]^T + bias, bf16 out.
// ---------------------------------------------------------------------------
__global__ __launch_bounds__(256) void proj_kernel(
    const float* __restrict__ main_feat, const float* __restrict__ Wq, const float* __restrict__ bq,
    const float* __restrict__ other_feat, const float* __restrict__ Wk, const float* __restrict__ bk,
    unsigned short* __restrict__ Qw, unsigned short* __restrict__ Kw)
{
    const float* src;  const float* W;  const float* bias;  unsigned short* dst;
    if (blockIdx.y == 0) { src = main_feat;  W = Wq; bias = bq; dst = Qw; }
    else                 { src = other_feat; W = Wk; bias = bk; dst = Kw; }

    const int wave = threadIdx.x >> 6, lane = threadIdx.x & 63;
    const int n = lane & 15, quad = lane >> 4;
    const int row0 = blockIdx.x * 64 + wave * 16;

    short8 a[8];
    const float* ap = src + (size_t)(row0 + n) * 256 + quad * 8;
#pragma unroll
    for (int ks = 0; ks < 8; ++ks) {
        float4 x0 = *(const float4*)(ap + ks * 32);
        float4 x1 = *(const float4*)(ap + ks * 32 + 4);
        a[ks] = cvt_f8_bf8(x0, x1);
    }

    floatx4 acc[8];
#pragma unroll
    for (int nt = 0; nt < 8; ++nt) acc[nt] = floatx4{0.f, 0.f, 0.f, 0.f};

#pragma unroll
    for (int nt = 0; nt < 8; ++nt) {
        const float* wp = W + (size_t)(nt * 16 + n) * 256 + quad * 8;
#pragma unroll
        for (int ks = 0; ks < 8; ++ks) {
            float4 w0 = *(const float4*)(wp + ks * 32);
            float4 w1 = *(const float4*)(wp + ks * 32 + 4);
            short8 b = cvt_f8_bf8(w0, w1);
            acc[nt] = MFMA16(a[ks], b, acc[nt]);
        }
    }

#pragma unroll
    for (int nt = 0; nt < 8; ++nt) {
        float bb = bias[nt * 16 + n];
#pragma unroll
        for (int reg = 0; reg < 4; ++reg) {
            int r = row0 + quad * 4 + reg;
            dst[(size_t)r * DMID + nt * 16 + n] = f2bf(acc[nt][reg] + bb);
        }
    }
}

// ---------------------------------------------------------------------------
// Vt[d][m] = fix[m] * other[m][d], bf16 (transposed for PV B-fragments).
// ---------------------------------------------------------------------------
__global__ __launch_bounds__(256) void build_vt_kernel(
    const float* __restrict__ other_feat, const float* __restrict__ fix_feat,
    unsigned short* __restrict__ Vt)
{
    __shared__ unsigned short tile[64 * 72];
    const int t = threadIdx.x;
    const int m0 = blockIdx.x * 64, d0 = blockIdx.y * 64;

#pragma unroll
    for (int r = 0; r < 4; ++r) {
        int idx = r * 256 + t;
        int ml = idx >> 4, dl4 = (idx & 15) * 4;
        float4 v = *(const float4*)(other_feat + (size_t)(m0 + ml) * 256 + d0 + dl4);
        float f = fix_feat[m0 + ml];
        tile[(dl4 + 0) * 72 + ml] = f2bf(v.x * f);
        tile[(dl4 + 1) * 72 + ml] = f2bf(v.y * f);
        tile[(dl4 + 2) * 72 + ml] = f2bf(v.z * f);
        tile[(dl4 + 3) * 72 + ml] = f2bf(v.w * f);
    }
    __syncthreads();
#pragma unroll
    for (int r = 0; r < 8; ++r) {
        int dl = r * 8 + (t >> 5);
        int ml = (t & 31) * 2;
        unsigned int v0 = tile[dl * 72 + ml];
        unsigned int v1 = tile[dl * 72 + ml + 1];
        *(unsigned int*)(Vt + (size_t)(d0 + dl) * M_KV + m0 + ml) = v0 | (v1 << 16);
    }
}

// ---------------------------------------------------------------------------
// Flash attention, NO online max (fixed m=0): logits*scale*log2e have
// |x| <~ 9 in log2 domain -> exp2 <= ~500, row sums <= ~4e6, safely fp32.
// Masked entries -> p = 0 exactly (cndmask after exp2), matching the
// reference's -(1<<32) masked_fill. l is a per-lane additive partial,
// reduced ONCE in the epilogue (no per-iter cross-lane ops at all).
// Split-K over M (nsplit chunks), partials combined by plain sums.
// ---------------------------------------------------------------------------
__global__ __launch_bounds__(256) void flash_kernel(
    const unsigned short* __restrict__ Qw, const unsigned short* __restrict__ Kw,
    const unsigned short* __restrict__ Vt, const unsigned long long* __restrict__ Mb,
    unsigned short* __restrict__ Opart, float* __restrict__ Lpart,
    int nsplit, int lgNs)
{
    __shared__ __align__(16) unsigned short k_lds[64 * 136];
    __shared__ __align__(16) unsigned short vt_lds[256 * 72];
    __shared__ __align__(16) unsigned short p_lds[4][32 * 72];

    const int L = blockIdx.x + gridDim.x * blockIdx.y;
    const int ly = L & (nsplit - 1);      // M-chunk id == XCD id (for nsplit=8)
    const int lx = L >> lgNs;             // Q-block id
    const int chunkLen = M_KV >> lgNs;
    const int mBeg = ly * chunkLen;
    const int tid = threadIdx.x;
    const int wave = tid >> 6, lane = tid & 63, n = lane & 15, quad = lane >> 4;
    const int qrow0 = lx * 128 + wave * 32;
    constexpr float SC = 0.08838834764831845f * 1.4426950408889634f; // scale*log2(e)

    short8 qf[2][4];
#pragma unroll
    for (int rt = 0; rt < 2; ++rt)
#pragma unroll
        for (int ks = 0; ks < 4; ++ks)
            qf[rt][ks] = *(const short8*)(Qw + (size_t)(qrow0 + rt * 16 + n) * DMID + ks * 32 + quad * 8);

    floatx4 Oacc[2][16];
#pragma unroll
    for (int rt = 0; rt < 2; ++rt)
#pragma unroll
        for (int dt = 0; dt < 16; ++dt) Oacc[rt][dt] = floatx4{0.f, 0.f, 0.f, 0.f};

    float lrow[2][4];
#pragma unroll
    for (int rt = 0; rt < 2; ++rt)
#pragma unroll
        for (int reg = 0; reg < 4; ++reg) lrow[rt][reg] = 0.f;

    const int iters = chunkLen / 64;
    for (int it = 0; it < iters; ++it) {
        const int m0 = mBeg + it * 64;
        __syncthreads();
#pragma unroll
        for (int r = 0; r < 4; ++r) {
            int idx = r * 256 + tid; int kr = idx >> 4, kc = idx & 15;
            *(short8*)&k_lds[kr * 136 + kc * 8] =
                *(const short8*)(Kw + (size_t)(m0 + kr) * DMID + kc * 8);
        }
#pragma unroll
        for (int r = 0; r < 8; ++r) {
            int idx = r * 256 + tid; int vr = idx >> 3, vc = idx & 7;
            *(short8*)&vt_lds[vr * 72 + vc * 8] =
                *(const short8*)(Vt + (size_t)vr * M_KV + m0 + vc * 8);
        }
        // mask bit words (overlap with staging)
        unsigned long long wbits[2][4];
#pragma unroll
        for (int rt = 0; rt < 2; ++rt)
#pragma unroll
            for (int reg = 0; reg < 4; ++reg)
                wbits[rt][reg] = Mb[(size_t)(qrow0 + rt * 16 + quad * 4 + reg) * MWORDS + (m0 >> 6)];
        __syncthreads();

        // ---- S = Q K^T ----
        floatx4 S[2][4];
#pragma unroll
        for (int rt = 0; rt < 2; ++rt)
#pragma unroll
            for (int nt = 0; nt < 4; ++nt) S[rt][nt] = floatx4{0.f, 0.f, 0.f, 0.f};

#pragma unroll
        for (int nt = 0; nt < 4; ++nt) {
            const int kb = (nt * 16 + n) * 136 + quad * 8;
            short8 b0 = *(const short8*)&k_lds[kb];
            short8 b1 = *(const short8*)&k_lds[kb + 32];
            short8 b2 = *(const short8*)&k_lds[kb + 64];
            short8 b3 = *(const short8*)&k_lds[kb + 96];
            S[0][nt] = MFMA16(qf[0][0], b0, S[0][nt]);
            S[0][nt] = MFMA16(qf[0][1], b1, S[0][nt]);
            S[0][nt] = MFMA16(qf[0][2], b2, S[0][nt]);
            S[0][nt] = MFMA16(qf[0][3], b3, S[0][nt]);
            S[1][nt] = MFMA16(qf[1][0], b0, S[1][nt]);
            S[1][nt] = MFMA16(qf[1][1], b1, S[1][nt]);
            S[1][nt] = MFMA16(qf[1][2], b2, S[1][nt]);
            S[1][nt] = MFMA16(qf[1][3], b3, S[1][nt]);
        }

        // ---- p = exp2(s*SC), zero where masked; accumulate l per-lane ----
#pragma unroll
        for (int rt = 0; rt < 2; ++rt) {
#pragma unroll
            for (int reg = 0; reg < 4; ++reg) {
                unsigned long long x = wbits[rt][reg] >> n;
                unsigned lo = (unsigned)x, hi = (unsigned)(x >> 32);
                float p0 = exp2f(S[rt][0][reg] * SC);
                float p1 = exp2f(S[rt][1][reg] * SC);
                float p2 = exp2f(S[rt][2][reg] * SC);
                float p3 = exp2f(S[rt][3][reg] * SC);
                p0 = (lo & 1u)         ? 0.f : p0;
                p1 = ((lo >> 16) & 1u) ? 0.f : p1;
                p2 = (hi & 1u)         ? 0.f : p2;
                p3 = ((hi >> 16) & 1u) ? 0.f : p3;
                lrow[rt][reg] += (p0 + p1) + (p2 + p3);
                S[rt][0][reg] = p0; S[rt][1][reg] = p1;
                S[rt][2][reg] = p2; S[rt][3][reg] = p3;
            }
#pragma unroll
            for (int nt = 0; nt < 4; ++nt)
#pragma unroll
                for (int reg = 0; reg < 4; ++reg)
                    p_lds[wave][(rt * 16 + quad * 4 + reg) * 72 + nt * 16 + n] = f2bf(S[rt][nt][reg]);
        }

        // ---- O += P V ----
#pragma unroll
        for (int kk = 0; kk < 2; ++kk) {
            short8 pa0 = *(const short8*)&p_lds[wave][(0 * 16 + n) * 72 + kk * 32 + quad * 8];
            short8 pa1 = *(const short8*)&p_lds[wave][(1 * 16 + n) * 72 + kk * 32 + quad * 8];
#pragma unroll
            for (int dt = 0; dt < 16; ++dt) {
                short8 bv = *(const short8*)&vt_lds[(dt * 16 + n) * 72 + kk * 32 + quad * 8];
                Oacc[0][dt] = MFMA16(pa0, bv, Oacc[0][dt]);
                Oacc[1][dt] = MFMA16(pa1, bv, Oacc[1][dt]);
            }
        }
    }

    // ---- epilogue: bf16 partials + one cross-lane l reduction ----
    const size_t obase = (size_t)ly * N_Q * DV;
#pragma unroll
    for (int rt = 0; rt < 2; ++rt)
#pragma unroll
        for (int dt = 0; dt < 16; ++dt)
#pragma unroll
            for (int reg = 0; reg < 4; ++reg) {
                int gr = qrow0 + rt * 16 + quad * 4 + reg;
                Opart[obase + (size_t)gr * DV + dt * 16 + n] = f2bf(Oacc[rt][dt][reg]);
            }
#pragma unroll
    for (int rt = 0; rt < 2; ++rt)
#pragma unroll
        for (int reg = 0; reg < 4; ++reg) {
            float r = lrow[rt][reg];
            r += __shfl_xor(r, 1);
            r += __shfl_xor(r, 2);
            r += __shfl_xor(r, 4);
            r += __shfl_xor(r, 8);
            lrow[rt][reg] = r;
        }
    if (n == 0) {
#pragma unroll
        for (int rt = 0; rt < 2; ++rt)
#pragma unroll
            for (int reg = 0; reg < 4; ++reg) {
                int gr = qrow0 + rt * 16 + quad * 4 + reg;
                Lpart[ly * N_Q + gr] = lrow[rt][reg];
            }
    }
}

// ---------------------------------------------------------------------------
// Combine: out = (sum_c O_c) / (sum_c l_c). Plain sums (no max weighting).
// ---------------------------------------------------------------------------
__global__ __launch_bounds__(256) void combine_kernel(
    const unsigned short* __restrict__ Opart, const float* __restrict__ Lpart,
    float* __restrict__ out, int nsplit)
{
    const int row = blockIdx.x, d = threadIdx.x;
    float L = 0.f, o = 0.f;
    for (int c = 0; c < nsplit; ++c) {
        L += Lpart[c * N_Q + row];
        unsigned int b = Opart[((size_t)c * N_Q + row) * DV + d];
        o += __uint_as_float(b << 16);
    }
    out[(size_t)row * DV + d] = o / L;
}

// ---------------------------------------------------------------------------
extern "C" void kernel_launch(void* const* d_in, const int* in_sizes, int n_in,
                              void* d_out, int out_size, void* d_ws, size_t ws_size,
                              hipStream_t stream)
{
    const float* main_feat  = (const float*)d_in[0];
    const float* other_feat = (const float*)d_in[1];
    const float* fix_feat   = (const float*)d_in[2];
    const void*  mask       = d_in[3];
    const float* Wq         = (const float*)d_in[4];
    const float* bq         = (const float*)d_in[5];
    const float* Wk         = (const float*)d_in[6];
    const float* bk         = (const float*)d_in[7];
    float* out = (float*)d_out;

    char* ws = (char*)d_ws;
    unsigned short* Qw = (unsigned short*)(ws);                         // 2 MB
    unsigned short* Kw = (unsigned short*)(ws + (1ull << 21));          // 2 MB
    unsigned short* Vt = (unsigned short*)(ws + (2ull << 21));          // 4 MB
    int* flag = (int*)(ws + (8ull << 20));
    unsigned long long* Mb = (unsigned long long*)(ws + (8ull << 20) + 1024);  // 8 MB
    float* Lpart = (float*)(ws + (16ull << 20) + 2048);

    const size_t base = (16ull << 20) + 2048;
    auto need = [&](int ns) {
        return base + (size_t)ns * N_Q * 4 + (size_t)ns * N_Q * DV * 2;
    };
    int nsplit = 1, lgNs = 0;
    if (ws_size >= need(8))      { nsplit = 8; lgNs = 3; }
    else if (ws_size >= need(4)) { nsplit = 4; lgNs = 2; }
    else if (ws_size >= need(2)) { nsplit = 2; lgNs = 1; }

    unsigned short* Opart = (unsigned short*)(Lpart + (size_t)nsplit * N_Q);

    hipLaunchKernelGGL(detect_mask_kernel, dim3(1), dim3(64), 0, stream,
                       (const unsigned int*)mask, flag);
    hipLaunchKernelGGL(pack_mask_kernel, dim3(N_Q * MWORDS / 256), dim3(256), 0, stream,
                       mask, flag, Mb);
    hipLaunchKernelGGL(proj_kernel, dim3(128, 2), dim3(256), 0, stream,
                       main_feat, Wq, bq, other_feat, Wk, bk, Qw, Kw);
    hipLaunchKernelGGL(build_vt_kernel, dim3(128, 4), dim3(256), 0, stream,
                       other_feat, fix_feat, Vt);
    hipLaunchKernelGGL(flash_kernel, dim3(64, nsplit), dim3(256), 0, stream,
                       Qw, Kw, Vt, Mb, Opart, Lpart, nsplit, lgNs);
    hipLaunchKernelGGL(combine_kernel, dim3(N_Q), dim3(256), 0, stream,
                       Opart, Lpart, out, nsplit);
}

// Round 5
// 603.707 us; speedup vs baseline: 1.0287x; 1.0287x over previous
//
#include <hip/hip_runtime.h>
#include <hip/hip_bf16.h>
#include <stdint.h>

typedef __attribute__((ext_vector_type(8))) short short8;
typedef __attribute__((ext_vector_type(4))) float floatx4;

#define MFMA32K(a, b, c) __builtin_amdgcn_mfma_f32_16x16x32_bf16(a, b, c, 0, 0, 0)

constexpr int N_Q  = 8192;
constexpr int M_KV = 8192;
constexpr int DMID = 128;
constexpr int DV   = 256;
constexpr int MWORDS = M_KV / 64;   // 128 u64 words per mask row

__device__ __forceinline__ unsigned short f2bf(float x) {
    unsigned u = __float_as_uint(x);
    u += 0x7fffu + ((u >> 16) & 1u);
    return (unsigned short)(u >> 16);
}

__device__ __forceinline__ short8 cvt_f8_bf8(float4 a, float4 b) {
    short8 r;
    r[0] = (short)f2bf(a.x); r[1] = (short)f2bf(a.y);
    r[2] = (short)f2bf(a.z); r[3] = (short)f2bf(a.w);
    r[4] = (short)f2bf(b.x); r[5] = (short)f2bf(b.y);
    r[6] = (short)f2bf(b.z); r[7] = (short)f2bf(b.w);
    return r;
}

// nonzero-byte -> 4-bit mask (bit i = byte i != 0)
__device__ __forceinline__ unsigned nz4(unsigned x) {
    unsigned nz = (((x & 0x7f7f7f7fu) + 0x7f7f7f7fu) | x) & 0x80808080u;
    unsigned a = (nz >> 7) & 0x01010101u;
    return (a * 0x01020408u) >> 24;   // b0 | b1<<1 | b2<<2 | b3<<3
}

// ---------------------------------------------------------------------------
// Mask dtype detection: 0 = int32 {0,1}, 1 = uint8 {0,1}, 2 = float32 {0,1}
// ---------------------------------------------------------------------------
__global__ void detect_mask_kernel(const unsigned int* __restrict__ mw, int* __restrict__ flag) {
    int t = threadIdx.x;
    unsigned w = mw[t];
    bool isf = (w == 0x3f800000u);
    bool isb = (w > 1u) && !isf;
    unsigned long long bf = __ballot(isf);
    unsigned long long bb = __ballot(isb);
    if (t == 0) *flag = bf ? 2 : (bb ? 1 : 0);
}

// ---------------------------------------------------------------------------
// Pack mask -> 1 bit per element. Coalesced u8 path: each wave loads 1KB
// contiguous per instruction, packs 16-bit pieces, routes through LDS,
// reads back as u64 (2-way LDS aliasing only = free).
// ---------------------------------------------------------------------------
__global__ __launch_bounds__(256) void pack_mask_kernel(
    const void* __restrict__ mask, const int* __restrict__ flagp,
    unsigned long long* __restrict__ Mb)
{
    const int tid = threadIdx.x;
    const int f = *flagp;
    const int wbase = blockIdx.x * 256;

    if (f == 1) {   // uint8 (the expected path)
        __shared__ unsigned short pbuf[1024];
        const uint4* g = (const uint4*)((const unsigned char*)mask + (size_t)wbase * 64);
        const int wv = tid >> 6, l = tid & 63;
#pragma unroll
        for (int r = 0; r < 4; ++r) {
            int p = wv * 256 + r * 64 + l;          // piece index in block
            uint4 v = g[p];
            unsigned m16 = nz4(v.x) | (nz4(v.y) << 4) | (nz4(v.z) << 8) | (nz4(v.w) << 12);
            pbuf[p] = (unsigned short)m16;
        }
        __syncthreads();
        Mb[wbase + tid] = ((const unsigned long long*)pbuf)[tid];
    } else {        // int32 or float32 {0,1}: nonzero test on raw bits
        unsigned long long bits = 0;
        const uint4* p = (const uint4*)((const unsigned int*)mask + (size_t)(wbase + tid) * 64);
#pragma unroll
        for (int i = 0; i < 16; ++i) {
            uint4 v = p[i];
            bits |= (unsigned long long)(v.x != 0) << (i * 4 + 0);
            bits |= (unsigned long long)(v.y != 0) << (i * 4 + 1);
            bits |= (unsigned long long)(v.z != 0) << (i * 4 + 2);
            bits |= (unsigned long long)(v.w != 0) << (i * 4 + 3);
        }
        Mb[wbase + tid] = bits;
    }
}

// ---------------------------------------------------------------------------
// Projections: dst[row,0:128] = src[row,0:256] @ W[128,256]^T + bias, bf16 out.
// ---------------------------------------------------------------------------
__global__ __launch_bounds__(256) void proj_kernel(
    const float* __restrict__ main_feat, const float* __restrict__ Wq, const float* __restrict__ bq,
    const float* __restrict__ other_feat, const float* __restrict__ Wk, const float* __restrict__ bk,
    unsigned short* __restrict__ Qw, unsigned short* __restrict__ Kw)
{
    const float* src;  const float* W;  const float* bias;  unsigned short* dst;
    if (blockIdx.y == 0) { src = main_feat;  W = Wq; bias = bq; dst = Qw; }
    else                 { src = other_feat; W = Wk; bias = bk; dst = Kw; }

    const int wave = threadIdx.x >> 6, lane = threadIdx.x & 63;
    const int n = lane & 15, quad = lane >> 4;
    const int row0 = blockIdx.x * 64 + wave * 16;

    short8 a[8];
    const float* ap = src + (size_t)(row0 + n) * 256 + quad * 8;
#pragma unroll
    for (int ks = 0; ks < 8; ++ks) {
        float4 x0 = *(const float4*)(ap + ks * 32);
        float4 x1 = *(const float4*)(ap + ks * 32 + 4);
        a[ks] = cvt_f8_bf8(x0, x1);
    }

    floatx4 acc[8];
#pragma unroll
    for (int nt = 0; nt < 8; ++nt) acc[nt] = floatx4{0.f, 0.f, 0.f, 0.f};

#pragma unroll
    for (int nt = 0; nt < 8; ++nt) {
        const float* wp = W + (size_t)(nt * 16 + n) * 256 + quad * 8;
#pragma unroll
        for (int ks = 0; ks < 8; ++ks) {
            float4 w0 = *(const float4*)(wp + ks * 32);
            float4 w1 = *(const float4*)(wp + ks * 32 + 4);
            short8 b = cvt_f8_bf8(w0, w1);
            acc[nt] = MFMA32K(a[ks], b, acc[nt]);
        }
    }

#pragma unroll
    for (int nt = 0; nt < 8; ++nt) {
        float bb = bias[nt * 16 + n];
#pragma unroll
        for (int reg = 0; reg < 4; ++reg) {
            int r = row0 + quad * 4 + reg;
            dst[(size_t)r * DMID + nt * 16 + n] = f2bf(acc[nt][reg] + bb);
        }
    }
}

// ---------------------------------------------------------------------------
// Vt[d][pc(m)] = fix[m] * other[m][d], bf16, transposed AND kv-permuted
// within each aligned 64-column group:
//   kv = 32e + 16s + 4q + j  ->  pc = 32e + 8q + 4s + j
// so that flash's PV B-fragments are single contiguous ds_read_b128 that
// match the register layout P naturally exits S^T in.
// ---------------------------------------------------------------------------
__global__ __launch_bounds__(256) void build_vt_kernel(
    const float* __restrict__ other_feat, const float* __restrict__ fix_feat,
    unsigned short* __restrict__ Vt)
{
    __shared__ unsigned short tile[64 * 72];
    const int t = threadIdx.x;
    const int m0 = blockIdx.x * 64, d0 = blockIdx.y * 64;

#pragma unroll
    for (int r = 0; r < 4; ++r) {
        int idx = r * 256 + t;
        int ml = idx >> 4, dl4 = (idx & 15) * 4;
        float4 v = *(const float4*)(other_feat + (size_t)(m0 + ml) * 256 + d0 + dl4);
        float f = fix_feat[m0 + ml];
        tile[(dl4 + 0) * 72 + ml] = f2bf(v.x * f);
        tile[(dl4 + 1) * 72 + ml] = f2bf(v.y * f);
        tile[(dl4 + 2) * 72 + ml] = f2bf(v.z * f);
        tile[(dl4 + 3) * 72 + ml] = f2bf(v.w * f);
    }
    __syncthreads();
#pragma unroll
    for (int r = 0; r < 8; ++r) {
        int dl = r * 8 + (t >> 5);
        int ml = (t & 31) * 2;   // even: pair stays inside one 4-group
        int pc = (ml & ~31) | ((ml & 12) << 1) | ((ml & 16) >> 2) | (ml & 3);
        unsigned int v0 = tile[dl * 72 + ml];
        unsigned int v1 = tile[dl * 72 + ml + 1];
        *(unsigned int*)(Vt + (size_t)(d0 + dl) * M_KV + m0 + pc) = v0 | (v1 << 16);
    }
}

// ---------------------------------------------------------------------------
// Flash attention, transposed-S, all-16x16x32 MFMA (no 16x16x16, no asm):
//   S^T = K·Q^T    (C-layout: kv = 16kvt + 4quad + reg, q = lane&15)
//   P = exp2(S^T*SC), 0 where masked, packed in-register to bf16.
//   PV: contraction-index permutation — P's natural layout IS the 16x16x32
//   A-layout under kv->pc permutation; Vt is stored pre-permuted, so the
//   B-fragment is one contiguous ds_read_b128. No P LDS round-trip.
// No online max (logits bounded, fp32-safe); l reduced once in epilogue.
// ---------------------------------------------------------------------------
__global__ __launch_bounds__(256) void flash_kernel(
    const unsigned short* __restrict__ Qw, const unsigned short* __restrict__ Kw,
    const unsigned short* __restrict__ Vt, const unsigned long long* __restrict__ Mb,
    unsigned short* __restrict__ Opart, float* __restrict__ Lpart,
    int nsplit, int lgNs)
{
    __shared__ __align__(16) unsigned short k_lds[64 * 136];   // [kv][d], stride 136
    __shared__ __align__(16) unsigned short vt_lds[256 * 72];  // [d][pc], stride 72

    const int L = blockIdx.x + gridDim.x * blockIdx.y;
    const int ly = L & (nsplit - 1);      // M-chunk id (XCD-L2 locality)
    const int lx = L >> lgNs;             // Q-block id
    const int chunkLen = M_KV >> lgNs;
    const int mBeg = ly * chunkLen;
    const int tid = threadIdx.x;
    const int wave = tid >> 6, lane = tid & 63, n = lane & 15, quad = lane >> 4;
    const int qrow0 = lx * 128 + wave * 32;
    constexpr float SC = 0.08838834764831845f * 1.4426950408889634f; // scale*log2(e)

    // Q fragments (B-operand for S^T)
    short8 qf[2][4];
#pragma unroll
    for (int qt = 0; qt < 2; ++qt)
#pragma unroll
        for (int db = 0; db < 4; ++db)
            qf[qt][db] = *(const short8*)(Qw + (size_t)(qrow0 + qt * 16 + n) * DMID + db * 32 + quad * 8);

    floatx4 Oacc[2][16];
#pragma unroll
    for (int qt = 0; qt < 2; ++qt)
#pragma unroll
        for (int dt = 0; dt < 16; ++dt) Oacc[qt][dt] = floatx4{0.f, 0.f, 0.f, 0.f};

    float lrow[2] = {0.f, 0.f};

    const int iters = chunkLen / 64;
    for (int it = 0; it < iters; ++it) {
        const int m0 = mBeg + it * 64;
        __syncthreads();
#pragma unroll
        for (int r = 0; r < 4; ++r) {
            int idx = r * 256 + tid; int kr = idx >> 4, kc = idx & 15;
            *(short8*)&k_lds[kr * 136 + kc * 8] =
                *(const short8*)(Kw + (size_t)(m0 + kr) * DMID + kc * 8);
        }
#pragma unroll
        for (int r = 0; r < 8; ++r) {
            int idx = r * 256 + tid; int vr = idx >> 3, vc = idx & 7;
            *(short8*)&vt_lds[vr * 72 + vc * 8] =
                *(const short8*)(Vt + (size_t)vr * M_KV + m0 + vc * 8);
        }
        // mask words (overlap with staging)
        unsigned long long wbits[2];
#pragma unroll
        for (int qt = 0; qt < 2; ++qt)
            wbits[qt] = Mb[(size_t)(qrow0 + qt * 16 + n) * MWORDS + (m0 >> 6)];
        __syncthreads();

        // ---- S^T = K Q^T ----
        floatx4 ST[4][2];
#pragma unroll
        for (int kvt = 0; kvt < 4; ++kvt) {
            const int kb = (kvt * 16 + n) * 136 + quad * 8;
            short8 a0 = *(const short8*)&k_lds[kb];
            short8 a1 = *(const short8*)&k_lds[kb + 32];
            short8 a2 = *(const short8*)&k_lds[kb + 64];
            short8 a3 = *(const short8*)&k_lds[kb + 96];
#pragma unroll
            for (int qt = 0; qt < 2; ++qt) {
                floatx4 s = floatx4{0.f, 0.f, 0.f, 0.f};
                s = MFMA32K(a0, qf[qt][0], s);
                s = MFMA32K(a1, qf[qt][1], s);
                s = MFMA32K(a2, qf[qt][2], s);
                s = MFMA32K(a3, qf[qt][3], s);
                ST[kvt][qt] = s;
            }
        }

        // ---- p = exp2(s*SC), 0 where masked; pack to 16x16x32 A-frags ----
        // pf8[qt][e] slot j: j<4 -> ST[2e] reg j (s=0), j>=4 -> ST[2e+1] reg j-4
        short8 pf8[2][2];
#pragma unroll
        for (int qt = 0; qt < 2; ++qt) {
            unsigned long long x = wbits[qt] >> (quad * 4);
            float lacc = 0.f;
#pragma unroll
            for (int kvt = 0; kvt < 4; ++kvt) {
                int e = kvt >> 1, s = kvt & 1;
#pragma unroll
                for (int j = 0; j < 4; ++j) {
                    float p = exp2f(ST[kvt][qt][j] * SC);
                    p = ((x >> (kvt * 16 + j)) & 1ull) ? 0.f : p;
                    lacc += p;
                    pf8[qt][e][s * 4 + j] = (short)f2bf(p);
                }
            }
            lrow[qt] += lacc;
        }

        // ---- O += P V  (16x16x32; B = contiguous b128 from permuted Vt) ----
#pragma unroll
        for (int e = 0; e < 2; ++e) {
#pragma unroll
            for (int dt = 0; dt < 16; ++dt) {
                short8 bv = *(const short8*)&vt_lds[(dt * 16 + n) * 72 + e * 32 + quad * 8];
                Oacc[0][dt] = MFMA32K(pf8[0][e], bv, Oacc[0][dt]);
                Oacc[1][dt] = MFMA32K(pf8[1][e], bv, Oacc[1][dt]);
            }
        }
    }

    // ---- epilogue: bf16 partials + cross-quad l reduction ----
    const size_t obase = (size_t)ly * N_Q * DV;
#pragma unroll
    for (int qt = 0; qt < 2; ++qt)
#pragma unroll
        for (int dt = 0; dt < 16; ++dt)
#pragma unroll
            for (int reg = 0; reg < 4; ++reg) {
                int gr = qrow0 + qt * 16 + quad * 4 + reg;
                Opart[obase + (size_t)gr * DV + dt * 16 + n] = f2bf(Oacc[qt][dt][reg]);
            }
#pragma unroll
    for (int qt = 0; qt < 2; ++qt) {
        float r = lrow[qt];
        r += __shfl_xor(r, 16);
        r += __shfl_xor(r, 32);
        if (quad == 0)
            Lpart[ly * N_Q + qrow0 + qt * 16 + n] = r;
    }
}

// ---------------------------------------------------------------------------
// Combine: out = (sum_c O_c) / (sum_c l_c).
// ---------------------------------------------------------------------------
__global__ __launch_bounds__(256) void combine_kernel(
    const unsigned short* __restrict__ Opart, const float* __restrict__ Lpart,
    float* __restrict__ out, int nsplit)
{
    const int row = blockIdx.x, d = threadIdx.x;
    float L = 0.f, o = 0.f;
    for (int c = 0; c < nsplit; ++c) {
        L += Lpart[c * N_Q + row];
        unsigned int b = Opart[((size_t)c * N_Q + row) * DV + d];
        o += __uint_as_float(b << 16);
    }
    out[(size_t)row * DV + d] = o / L;
}

// ---------------------------------------------------------------------------
extern "C" void kernel_launch(void* const* d_in, const int* in_sizes, int n_in,
                              void* d_out, int out_size, void* d_ws, size_t ws_size,
                              hipStream_t stream)
{
    const float* main_feat  = (const float*)d_in[0];
    const float* other_feat = (const float*)d_in[1];
    const float* fix_feat   = (const float*)d_in[2];
    const void*  mask       = d_in[3];
    const float* Wq         = (const float*)d_in[4];
    const float* bq         = (const float*)d_in[5];
    const float* Wk         = (const float*)d_in[6];
    const float* bk         = (const float*)d_in[7];
    float* out = (float*)d_out;

    char* ws = (char*)d_ws;
    unsigned short* Qw = (unsigned short*)(ws);                         // 2 MB
    unsigned short* Kw = (unsigned short*)(ws + (1ull << 21));          // 2 MB
    unsigned short* Vt = (unsigned short*)(ws + (2ull << 21));          // 4 MB
    int* flag = (int*)(ws + (8ull << 20));
    unsigned long long* Mb = (unsigned long long*)(ws + (8ull << 20) + 1024);  // 8 MB
    float* Lpart = (float*)(ws + (16ull << 20) + 2048);

    const size_t base = (16ull << 20) + 2048;
    auto need = [&](int ns) {
        return base + (size_t)ns * N_Q * 4 + (size_t)ns * N_Q * DV * 2;
    };
    int nsplit = 1, lgNs = 0;
    if (ws_size >= need(8))      { nsplit = 8; lgNs = 3; }
    else if (ws_size >= need(4)) { nsplit = 4; lgNs = 2; }
    else if (ws_size >= need(2)) { nsplit = 2; lgNs = 1; }

    unsigned short* Opart = (unsigned short*)(Lpart + (size_t)nsplit * N_Q);

    hipLaunchKernelGGL(detect_mask_kernel, dim3(1), dim3(64), 0, stream,
                       (const unsigned int*)mask, flag);
    hipLaunchKernelGGL(pack_mask_kernel, dim3(N_Q * MWORDS / 256), dim3(256), 0, stream,
                       mask, flag, Mb);
    hipLaunchKernelGGL(proj_kernel, dim3(128, 2), dim3(256), 0, stream,
                       main_feat, Wq, bq, other_feat, Wk, bk, Qw, Kw);
    hipLaunchKernelGGL(build_vt_kernel, dim3(128, 4), dim3(256), 0, stream,
                       other_feat, fix_feat, Vt);
    hipLaunchKernelGGL(flash_kernel, dim3(64, nsplit), dim3(256), 0, stream,
                       Qw, Kw, Vt, Mb, Opart, Lpart, nsplit, lgNs);
    hipLaunchKernelGGL(combine_kernel, dim3(N_Q), dim3(256), 0, stream,
                       Opart, Lpart, out, nsplit);
}

// Round 6
// 497.292 us; speedup vs baseline: 1.2489x; 1.2140x over previous
//
#include <hip/hip_runtime.h>
#include <hip/hip_bf16.h>
#include <stdint.h>

typedef __attribute__((ext_vector_type(8))) short short8;
typedef __attribute__((ext_vector_type(4))) float floatx4;

#define MFMA32K(a, b, c) __builtin_amdgcn_mfma_f32_16x16x32_bf16(a, b, c, 0, 0, 0)

constexpr int N_Q  = 8192;
constexpr int M_KV = 8192;
constexpr int DMID = 128;
constexpr int DV   = 256;
constexpr int MWORDS = M_KV / 64;   // 128 u64 words per mask row

__device__ __forceinline__ unsigned short f2bf(float x) {
    unsigned u = __float_as_uint(x);
    u += 0x7fffu + ((u >> 16) & 1u);
    return (unsigned short)(u >> 16);
}

__device__ __forceinline__ short8 cvt_f8_bf8(float4 a, float4 b) {
    short8 r;
    r[0] = (short)f2bf(a.x); r[1] = (short)f2bf(a.y);
    r[2] = (short)f2bf(a.z); r[3] = (short)f2bf(a.w);
    r[4] = (short)f2bf(b.x); r[5] = (short)f2bf(b.y);
    r[6] = (short)f2bf(b.z); r[7] = (short)f2bf(b.w);
    return r;
}

// async global->LDS, 16B per lane; lds dst MUST be wave-uniform (HW adds lane*16)
__device__ __forceinline__ void gl_lds16(const unsigned short* g, unsigned short* l) {
    __builtin_amdgcn_global_load_lds(
        (const __attribute__((address_space(1))) unsigned int*)g,
        (__attribute__((address_space(3))) unsigned int*)l, 16, 0, 0);
}

// nonzero-byte -> 4-bit mask (bit i = byte i != 0)
__device__ __forceinline__ unsigned nz4(unsigned x) {
    unsigned nz = (((x & 0x7f7f7f7fu) + 0x7f7f7f7fu) | x) & 0x80808080u;
    unsigned a = (nz >> 7) & 0x01010101u;
    return (a * 0x01020408u) >> 24;
}

// ---------------------------------------------------------------------------
// Mask dtype detection: 0 = int32 {0,1}, 1 = uint8 {0,1}, 2 = float32 {0,1}
// ---------------------------------------------------------------------------
__global__ void detect_mask_kernel(const unsigned int* __restrict__ mw, int* __restrict__ flag) {
    int t = threadIdx.x;
    unsigned w = mw[t];
    bool isf = (w == 0x3f800000u);
    bool isb = (w > 1u) && !isf;
    unsigned long long bf = __ballot(isf);
    unsigned long long bb = __ballot(isb);
    if (t == 0) *flag = bf ? 2 : (bb ? 1 : 0);
}

// ---------------------------------------------------------------------------
// Pack mask -> 1 bit per element. Block covers 256 u64 words in all paths.
// int32/f32 path: lane loads one element (fully coalesced 256B/wave),
// __ballot(v!=0) IS the output word. u8 path: coalesced uint4 + LDS gather.
// ---------------------------------------------------------------------------
__global__ __launch_bounds__(256) void pack_mask_kernel(
    const void* __restrict__ mask, const int* __restrict__ flagp,
    unsigned long long* __restrict__ Mb)
{
    const int tid = threadIdx.x;
    const int f = *flagp;
    const int wbase = blockIdx.x * 256;
    const int wv = tid >> 6, lane = tid & 63;

    if (f == 1) {   // uint8
        __shared__ unsigned short pbuf[1024];
        const uint4* g = (const uint4*)((const unsigned char*)mask + (size_t)wbase * 64);
#pragma unroll
        for (int r = 0; r < 4; ++r) {
            int p = wv * 256 + r * 64 + lane;
            uint4 v = g[p];
            unsigned m16 = nz4(v.x) | (nz4(v.y) << 4) | (nz4(v.z) << 8) | (nz4(v.w) << 12);
            pbuf[p] = (unsigned short)m16;
        }
        __syncthreads();
        Mb[wbase + tid] = ((const unsigned long long*)pbuf)[tid];
    } else {        // 32-bit elements (int32 or f32): ballot per word
        const unsigned int* mp = (const unsigned int*)mask;
        const int w0 = wbase + wv * 64;
#pragma unroll 4
        for (int i = 0; i < 64; ++i) {
            unsigned v = mp[(size_t)(w0 + i) * 64 + lane];
            unsigned long long b = __ballot(v != 0u);
            if (lane == 0) Mb[w0 + i] = b;
        }
    }
}

// ---------------------------------------------------------------------------
// Projections: dst[row] = src[row] @ W^T + bias, bf16, stored with 16B-unit
// rotation within the row:  unit' = (unit + row) & 15  (bank-conflict-free
// LDS reads in flash with unpadded stride-128 tiles).
// ---------------------------------------------------------------------------
__global__ __launch_bounds__(256) void proj_kernel(
    const float* __restrict__ main_feat, const float* __restrict__ Wq, const float* __restrict__ bq,
    const float* __restrict__ other_feat, const float* __restrict__ Wk, const float* __restrict__ bk,
    unsigned short* __restrict__ Qw, unsigned short* __restrict__ Kw)
{
    const float* src;  const float* W;  const float* bias;  unsigned short* dst;
    if (blockIdx.y == 0) { src = main_feat;  W = Wq; bias = bq; dst = Qw; }
    else                 { src = other_feat; W = Wk; bias = bk; dst = Kw; }

    const int wave = threadIdx.x >> 6, lane = threadIdx.x & 63;
    const int n = lane & 15, quad = lane >> 4;
    const int row0 = blockIdx.x * 64 + wave * 16;

    short8 a[8];
    const float* ap = src + (size_t)(row0 + n) * 256 + quad * 8;
#pragma unroll
    for (int ks = 0; ks < 8; ++ks) {
        float4 x0 = *(const float4*)(ap + ks * 32);
        float4 x1 = *(const float4*)(ap + ks * 32 + 4);
        a[ks] = cvt_f8_bf8(x0, x1);
    }

    floatx4 acc[8];
#pragma unroll
    for (int nt = 0; nt < 8; ++nt) acc[nt] = floatx4{0.f, 0.f, 0.f, 0.f};

#pragma unroll
    for (int nt = 0; nt < 8; ++nt) {
        const float* wp = W + (size_t)(nt * 16 + n) * 256 + quad * 8;
#pragma unroll
        for (int ks = 0; ks < 8; ++ks) {
            float4 w0 = *(const float4*)(wp + ks * 32);
            float4 w1 = *(const float4*)(wp + ks * 32 + 4);
            short8 b = cvt_f8_bf8(w0, w1);
            acc[nt] = MFMA32K(a[ks], b, acc[nt]);
        }
    }

#pragma unroll
    for (int nt = 0; nt < 8; ++nt) {
        float bb = bias[nt * 16 + n];
#pragma unroll
        for (int reg = 0; reg < 4; ++reg) {
            int r = row0 + quad * 4 + reg;
            int c = nt * 16 + n;
            int phys = ((((c >> 3) + r) & 15) << 3) | (c & 7);
            dst[(size_t)r * DMID + phys] = f2bf(acc[nt][reg] + bb);
        }
    }
}

// ---------------------------------------------------------------------------
// Vt[d][col(m)] = fix[m] * other[m][d], bf16 transposed; column mapping =
// pc-permutation (PV contraction match: kv=32e+16s+4q+j -> pc=32e+8q+4s+j)
// composed with 16B-unit rotation by d within each 64-col group.
// ---------------------------------------------------------------------------
__global__ __launch_bounds__(256) void build_vt_kernel(
    const float* __restrict__ other_feat, const float* __restrict__ fix_feat,
    unsigned short* __restrict__ Vt)
{
    __shared__ unsigned short tile[64 * 72];
    const int t = threadIdx.x;
    const int m0 = blockIdx.x * 64, d0 = blockIdx.y * 64;

#pragma unroll
    for (int r = 0; r < 4; ++r) {
        int idx = r * 256 + t;
        int ml = idx >> 4, dl4 = (idx & 15) * 4;
        float4 v = *(const float4*)(other_feat + (size_t)(m0 + ml) * 256 + d0 + dl4);
        float f = fix_feat[m0 + ml];
        tile[(dl4 + 0) * 72 + ml] = f2bf(v.x * f);
        tile[(dl4 + 1) * 72 + ml] = f2bf(v.y * f);
        tile[(dl4 + 2) * 72 + ml] = f2bf(v.z * f);
        tile[(dl4 + 3) * 72 + ml] = f2bf(v.w * f);
    }
    __syncthreads();
#pragma unroll
    for (int r = 0; r < 8; ++r) {
        int dl = r * 8 + (t >> 5);
        int d = d0 + dl;
        int ml = (t & 31) * 2;               // logical kv (even pair base)
        int e = ml >> 5, s = (ml >> 4) & 1, q = (ml >> 2) & 3, j = ml & 3;
        int pc = e * 32 + q * 8 + s * 4 + j; // contraction permutation
        int phys = ((((pc >> 3) + d) & 7) << 3) | (pc & 7);  // unit rotation by d
        unsigned int v0 = tile[dl * 72 + ml];
        unsigned int v1 = tile[dl * 72 + ml + 1];
        *(unsigned int*)(Vt + (size_t)d * M_KV + m0 + phys) = v0 | (v1 << 16);
    }
}

// ---------------------------------------------------------------------------
// Flash attention. Register-lean build for 2 waves/SIMD:
//  - K/Vt staged via global_load_lds (no VGPR round-trip, unpadded strides;
//    bank conflicts avoided by the global-side unit rotations above)
//  - S^T = K.Q^T (16x16x32), P packed in-register (v_cvt_pk via
//    __float22bfloat162_rn), PV on 16x16x32 with pc-permuted Vt
//  - no online max (logits bounded); l reduced once in epilogue
// ---------------------------------------------------------------------------
__global__ __launch_bounds__(256, 2) void flash_kernel(
    const unsigned short* __restrict__ Qw, const unsigned short* __restrict__ Kw,
    const unsigned short* __restrict__ Vt, const unsigned long long* __restrict__ Mb,
    unsigned short* __restrict__ Opart, float* __restrict__ Lpart,
    int nsplit, int lgNs)
{
    __shared__ __align__(16) unsigned short k_lds[64 * 128];   // 16 KB, unit-rotated rows
    __shared__ __align__(16) unsigned short vt_lds[256 * 64];  // 32 KB, pc+rot columns

    const int L = blockIdx.x + gridDim.x * blockIdx.y;
    const int ly = L & (nsplit - 1);
    const int lx = L >> lgNs;
    const int chunkLen = M_KV >> lgNs;
    const int mBeg = ly * chunkLen;
    const int tid = threadIdx.x;
    const int wave = tid >> 6, lane = tid & 63, n = lane & 15, quad = lane >> 4;
    const int qrow0 = lx * 128 + wave * 32;
    constexpr float SC = 0.08838834764831845f * 1.4426950408889634f; // scale*log2(e)

    // Q fragments (rotated layout: unit' = (unit + row) & 15)
    short8 qf[2][4];
#pragma unroll
    for (int qt = 0; qt < 2; ++qt)
#pragma unroll
        for (int db = 0; db < 4; ++db) {
            int row = qrow0 + qt * 16 + n;
            int phys = (db * 4 + quad + row) & 15;
            qf[qt][db] = *(const short8*)(Qw + (size_t)row * DMID + phys * 8);
        }

    floatx4 Oacc[2][16];
#pragma unroll
    for (int qt = 0; qt < 2; ++qt)
#pragma unroll
        for (int dt = 0; dt < 16; ++dt) Oacc[qt][dt] = floatx4{0.f, 0.f, 0.f, 0.f};

    float lrow[2] = {0.f, 0.f};

    // staging address invariants (global side is per-lane; LDS side wave-uniform)
    const unsigned short* kg = Kw + (size_t)(wave * 4 + (lane >> 4)) * DMID + (lane & 15) * 8;
    const unsigned short* vg = Vt + (size_t)(wave * 8 + (lane >> 3)) * M_KV + (lane & 7) * 8;
    unsigned short* kld = &k_lds[wave * 512];
    unsigned short* vld = &vt_lds[wave * 512];
    const int kqn = quad + n;   // for rotated k_lds reads

    const int iters = chunkLen / 64;
    for (int it = 0; it < iters; ++it) {
        const int m0 = mBeg + it * 64;
        __syncthreads();
        // K tile: 16 segs of 1KB (seg = r*4+wave -> 4 rows each)
#pragma unroll
        for (int r = 0; r < 4; ++r)
            gl_lds16(kg + (size_t)(m0 + r * 16) * DMID, kld + r * 2048);
        // Vt tile: 32 segs of 1KB (seg = r*4+wave -> 8 d-rows each)
#pragma unroll
        for (int r = 0; r < 8; ++r)
            gl_lds16(vg + (size_t)(r * 32) * M_KV + m0, vld + r * 2048);
        // mask words (overlap with DMA)
        unsigned long long wbits[2];
#pragma unroll
        for (int qt = 0; qt < 2; ++qt)
            wbits[qt] = Mb[(size_t)(qrow0 + qt * 16 + n) * MWORDS + (m0 >> 6)];
        __syncthreads();

        // ---- S^T = K Q^T (kv = 16kvt + 4quad + reg, q = n) ----
        floatx4 ST[4][2];
#pragma unroll
        for (int kvt = 0; kvt < 4; ++kvt) {
            const int rowoff = (kvt * 16 + n) * DMID;
            short8 a0 = *(const short8*)&k_lds[rowoff + (((kqn + 0) & 15) << 3)];
            short8 a1 = *(const short8*)&k_lds[rowoff + (((kqn + 4) & 15) << 3)];
            short8 a2 = *(const short8*)&k_lds[rowoff + (((kqn + 8) & 15) << 3)];
            short8 a3 = *(const short8*)&k_lds[rowoff + (((kqn + 12) & 15) << 3)];
#pragma unroll
            for (int qt = 0; qt < 2; ++qt) {
                floatx4 s = floatx4{0.f, 0.f, 0.f, 0.f};
                s = MFMA32K(a0, qf[qt][0], s);
                s = MFMA32K(a1, qf[qt][1], s);
                s = MFMA32K(a2, qf[qt][2], s);
                s = MFMA32K(a3, qf[qt][3], s);
                ST[kvt][qt] = s;
            }
        }

        // ---- p = exp2(s*SC), 0 where masked; pack to A-frags (v_cvt_pk) ----
        short8 pf8[2][2];
#pragma unroll
        for (int qt = 0; qt < 2; ++qt) {
            unsigned long long x = wbits[qt] >> (quad * 4);
            float lacc = 0.f;
#pragma unroll
            for (int kvt = 0; kvt < 4; ++kvt) {
                int e = kvt >> 1, s = kvt & 1;
                float p[4];
#pragma unroll
                for (int j = 0; j < 4; ++j) {
                    float v = __builtin_amdgcn_exp2f(ST[kvt][qt][j] * SC);
                    p[j] = ((x >> (kvt * 16 + j)) & 1ull) ? 0.f : v;
                    lacc += p[j];
                }
                __hip_bfloat162 h0 = __float22bfloat162_rn(make_float2(p[0], p[1]));
                __hip_bfloat162 h1 = __float22bfloat162_rn(make_float2(p[2], p[3]));
                unsigned u0, u1;
                __builtin_memcpy(&u0, &h0, 4);
                __builtin_memcpy(&u1, &h1, 4);
                ((unsigned*)&pf8[qt][e])[s * 2 + 0] = u0;
                ((unsigned*)&pf8[qt][e])[s * 2 + 1] = u1;
            }
            lrow[qt] += lacc;
        }

        // ---- O += P V (B-frag: rotated contiguous b128 from vt_lds) ----
#pragma unroll
        for (int e = 0; e < 2; ++e) {
#pragma unroll
            for (int dt = 0; dt < 16; ++dt) {
                const int vb = (dt * 16 + n) * 64 + (((e * 4 + quad + n) & 7) << 3);
                short8 bv = *(const short8*)&vt_lds[vb];
                Oacc[0][dt] = MFMA32K(pf8[0][e], bv, Oacc[0][dt]);
                Oacc[1][dt] = MFMA32K(pf8[1][e], bv, Oacc[1][dt]);
            }
        }
    }

    // ---- epilogue: bf16 partials + cross-quad l reduction ----
    const size_t obase = (size_t)ly * N_Q * DV;
#pragma unroll
    for (int qt = 0; qt < 2; ++qt)
#pragma unroll
        for (int dt = 0; dt < 16; ++dt)
#pragma unroll
            for (int reg = 0; reg < 4; ++reg) {
                int gr = qrow0 + qt * 16 + quad * 4 + reg;
                Opart[obase + (size_t)gr * DV + dt * 16 + n] = f2bf(Oacc[qt][dt][reg]);
            }
#pragma unroll
    for (int qt = 0; qt < 2; ++qt) {
        float r = lrow[qt];
        r += __shfl_xor(r, 16);
        r += __shfl_xor(r, 32);
        if (quad == 0)
            Lpart[ly * N_Q + qrow0 + qt * 16 + n] = r;
    }
}

// ---------------------------------------------------------------------------
// Combine: out = (sum_c O_c) / (sum_c l_c).
// ---------------------------------------------------------------------------
__global__ __launch_bounds__(256) void combine_kernel(
    const unsigned short* __restrict__ Opart, const float* __restrict__ Lpart,
    float* __restrict__ out, int nsplit)
{
    const int row = blockIdx.x, d = threadIdx.x;
    float L = 0.f, o = 0.f;
    for (int c = 0; c < nsplit; ++c) {
        L += Lpart[c * N_Q + row];
        unsigned int b = Opart[((size_t)c * N_Q + row) * DV + d];
        o += __uint_as_float(b << 16);
    }
    out[(size_t)row * DV + d] = o / L;
}

// ---------------------------------------------------------------------------
extern "C" void kernel_launch(void* const* d_in, const int* in_sizes, int n_in,
                              void* d_out, int out_size, void* d_ws, size_t ws_size,
                              hipStream_t stream)
{
    const float* main_feat  = (const float*)d_in[0];
    const float* other_feat = (const float*)d_in[1];
    const float* fix_feat   = (const float*)d_in[2];
    const void*  mask       = d_in[3];
    const float* Wq         = (const float*)d_in[4];
    const float* bq         = (const float*)d_in[5];
    const float* Wk         = (const float*)d_in[6];
    const float* bk         = (const float*)d_in[7];
    float* out = (float*)d_out;

    char* ws = (char*)d_ws;
    unsigned short* Qw = (unsigned short*)(ws);                         // 2 MB
    unsigned short* Kw = (unsigned short*)(ws + (1ull << 21));          // 2 MB
    unsigned short* Vt = (unsigned short*)(ws + (2ull << 21));          // 4 MB
    int* flag = (int*)(ws + (8ull << 20));
    unsigned long long* Mb = (unsigned long long*)(ws + (8ull << 20) + 1024);  // 8 MB
    float* Lpart = (float*)(ws + (16ull << 20) + 2048);

    const size_t base = (16ull << 20) + 2048;
    auto need = [&](int ns) {
        return base + (size_t)ns * N_Q * 4 + (size_t)ns * N_Q * DV * 2;
    };
    int nsplit = 1, lgNs = 0;
    if (ws_size >= need(8))      { nsplit = 8; lgNs = 3; }
    else if (ws_size >= need(4)) { nsplit = 4; lgNs = 2; }
    else if (ws_size >= need(2)) { nsplit = 2; lgNs = 1; }

    unsigned short* Opart = (unsigned short*)(Lpart + (size_t)nsplit * N_Q);

    hipLaunchKernelGGL(detect_mask_kernel, dim3(1), dim3(64), 0, stream,
                       (const unsigned int*)mask, flag);
    hipLaunchKernelGGL(pack_mask_kernel, dim3(N_Q * MWORDS / 256), dim3(256), 0, stream,
                       mask, flag, Mb);
    hipLaunchKernelGGL(proj_kernel, dim3(128, 2), dim3(256), 0, stream,
                       main_feat, Wq, bq, other_feat, Wk, bk, Qw, Kw);
    hipLaunchKernelGGL(build_vt_kernel, dim3(128, 4), dim3(256), 0, stream,
                       other_feat, fix_feat, Vt);
    hipLaunchKernelGGL(flash_kernel, dim3(64, nsplit), dim3(256), 0, stream,
                       Qw, Kw, Vt, Mb, Opart, Lpart, nsplit, lgNs);
    hipLaunchKernelGGL(combine_kernel, dim3(N_Q), dim3(256), 0, stream,
                       Opart, Lpart, out, nsplit);
}

// Round 7
// 497.083 us; speedup vs baseline: 1.2494x; 1.0004x over previous
//
#include <hip/hip_runtime.h>
#include <hip/hip_bf16.h>
#include <stdint.h>

typedef __attribute__((ext_vector_type(8))) short short8;
typedef __attribute__((ext_vector_type(4))) float floatx4;

#define MFMA32K(a, b, c) __builtin_amdgcn_mfma_f32_16x16x32_bf16(a, b, c, 0, 0, 0)

constexpr int N_Q  = 8192;
constexpr int M_KV = 8192;
constexpr int DMID = 128;
constexpr int DV   = 256;
constexpr int MWORDS = M_KV / 64;   // 128 u64 words per mask row

__device__ __forceinline__ unsigned short f2bf(float x) {
    unsigned u = __float_as_uint(x);
    u += 0x7fffu + ((u >> 16) & 1u);
    return (unsigned short)(u >> 16);
}

__device__ __forceinline__ short8 cvt_f8_bf8(float4 a, float4 b) {
    short8 r;
    r[0] = (short)f2bf(a.x); r[1] = (short)f2bf(a.y);
    r[2] = (short)f2bf(a.z); r[3] = (short)f2bf(a.w);
    r[4] = (short)f2bf(b.x); r[5] = (short)f2bf(b.y);
    r[6] = (short)f2bf(b.z); r[7] = (short)f2bf(b.w);
    return r;
}

// async global->LDS, 16B per lane; lds dst is wave-uniform (HW adds lane*16)
__device__ __forceinline__ void gl_lds16(const unsigned short* g, unsigned short* l) {
    __builtin_amdgcn_global_load_lds(
        (const __attribute__((address_space(1))) unsigned int*)g,
        (__attribute__((address_space(3))) unsigned int*)l, 16, 0, 0);
}

// nonzero-byte -> 4-bit mask (bit i = byte i != 0)
__device__ __forceinline__ unsigned nz4(unsigned x) {
    unsigned nz = (((x & 0x7f7f7f7fu) + 0x7f7f7f7fu) | x) & 0x80808080u;
    unsigned a = (nz >> 7) & 0x01010101u;
    return (a * 0x01020408u) >> 24;
}

// ---------------------------------------------------------------------------
// Mask dtype detection: 0 = int32 {0,1}, 1 = uint8 {0,1}, 2 = float32 {0,1}
// ---------------------------------------------------------------------------
__global__ void detect_mask_kernel(const unsigned int* __restrict__ mw, int* __restrict__ flag) {
    int t = threadIdx.x;
    unsigned w = mw[t];
    bool isf = (w == 0x3f800000u);
    bool isb = (w > 1u) && !isf;
    unsigned long long bf = __ballot(isf);
    unsigned long long bb = __ballot(isb);
    if (t == 0) *flag = bf ? 2 : (bb ? 1 : 0);
}

// ---------------------------------------------------------------------------
// Pack mask -> 1 bit per element. int32/f32: coalesced lane-per-element +
// __ballot. uint8: coalesced uint4 + LDS gather.
// ---------------------------------------------------------------------------
__global__ __launch_bounds__(256) void pack_mask_kernel(
    const void* __restrict__ mask, const int* __restrict__ flagp,
    unsigned long long* __restrict__ Mb)
{
    const int tid = threadIdx.x;
    const int f = *flagp;
    const int wbase = blockIdx.x * 256;
    const int wv = tid >> 6, lane = tid & 63;

    if (f == 1) {   // uint8
        __shared__ unsigned short pbuf[1024];
        const uint4* g = (const uint4*)((const unsigned char*)mask + (size_t)wbase * 64);
#pragma unroll
        for (int r = 0; r < 4; ++r) {
            int p = wv * 256 + r * 64 + lane;
            uint4 v = g[p];
            unsigned m16 = nz4(v.x) | (nz4(v.y) << 4) | (nz4(v.z) << 8) | (nz4(v.w) << 12);
            pbuf[p] = (unsigned short)m16;
        }
        __syncthreads();
        Mb[wbase + tid] = ((const unsigned long long*)pbuf)[tid];
    } else {        // 32-bit elements (int32 or f32): ballot per word
        const unsigned int* mp = (const unsigned int*)mask;
        const int w0 = wbase + wv * 64;
#pragma unroll 4
        for (int i = 0; i < 64; ++i) {
            unsigned v = mp[(size_t)(w0 + i) * 64 + lane];
            unsigned long long b = __ballot(v != 0u);
            if (lane == 0) Mb[w0 + i] = b;
        }
    }
}

// ---------------------------------------------------------------------------
// Projections: dst[row] = src[row] @ W^T + bias, bf16, 16B-unit rotation
// within the row: unit' = (unit + row) & 15.
// ---------------------------------------------------------------------------
__global__ __launch_bounds__(256) void proj_kernel(
    const float* __restrict__ main_feat, const float* __restrict__ Wq, const float* __restrict__ bq,
    const float* __restrict__ other_feat, const float* __restrict__ Wk, const float* __restrict__ bk,
    unsigned short* __restrict__ Qw, unsigned short* __restrict__ Kw)
{
    const float* src;  const float* W;  const float* bias;  unsigned short* dst;
    if (blockIdx.y == 0) { src = main_feat;  W = Wq; bias = bq; dst = Qw; }
    else                 { src = other_feat; W = Wk; bias = bk; dst = Kw; }

    const int wave = threadIdx.x >> 6, lane = threadIdx.x & 63;
    const int n = lane & 15, quad = lane >> 4;
    const int row0 = blockIdx.x * 64 + wave * 16;

    short8 a[8];
    const float* ap = src + (size_t)(row0 + n) * 256 + quad * 8;
#pragma unroll
    for (int ks = 0; ks < 8; ++ks) {
        float4 x0 = *(const float4*)(ap + ks * 32);
        float4 x1 = *(const float4*)(ap + ks * 32 + 4);
        a[ks] = cvt_f8_bf8(x0, x1);
    }

    floatx4 acc[8];
#pragma unroll
    for (int nt = 0; nt < 8; ++nt) acc[nt] = floatx4{0.f, 0.f, 0.f, 0.f};

#pragma unroll
    for (int nt = 0; nt < 8; ++nt) {
        const float* wp = W + (size_t)(nt * 16 + n) * 256 + quad * 8;
#pragma unroll
        for (int ks = 0; ks < 8; ++ks) {
            float4 w0 = *(const float4*)(wp + ks * 32);
            float4 w1 = *(const float4*)(wp + ks * 32 + 4);
            short8 b = cvt_f8_bf8(w0, w1);
            acc[nt] = MFMA32K(a[ks], b, acc[nt]);
        }
    }

#pragma unroll
    for (int nt = 0; nt < 8; ++nt) {
        float bb = bias[nt * 16 + n];
#pragma unroll
        for (int reg = 0; reg < 4; ++reg) {
            int r = row0 + quad * 4 + reg;
            int c = nt * 16 + n;
            int phys = ((((c >> 3) + r) & 15) << 3) | (c & 7);
            dst[(size_t)r * DMID + phys] = f2bf(acc[nt][reg] + bb);
        }
    }
}

// ---------------------------------------------------------------------------
// Vt[d][col(m)] = fix[m] * other[m][d]; col = pc-permutation (kv=32e+16s+4q+j
// -> pc=32e+8q+4s+j) composed with 16B-unit rotation by d per 64-col group.
// ---------------------------------------------------------------------------
__global__ __launch_bounds__(256) void build_vt_kernel(
    const float* __restrict__ other_feat, const float* __restrict__ fix_feat,
    unsigned short* __restrict__ Vt)
{
    __shared__ unsigned short tile[64 * 72];
    const int t = threadIdx.x;
    const int m0 = blockIdx.x * 64, d0 = blockIdx.y * 64;

#pragma unroll
    for (int r = 0; r < 4; ++r) {
        int idx = r * 256 + t;
        int ml = idx >> 4, dl4 = (idx & 15) * 4;
        float4 v = *(const float4*)(other_feat + (size_t)(m0 + ml) * 256 + d0 + dl4);
        float f = fix_feat[m0 + ml];
        tile[(dl4 + 0) * 72 + ml] = f2bf(v.x * f);
        tile[(dl4 + 1) * 72 + ml] = f2bf(v.y * f);
        tile[(dl4 + 2) * 72 + ml] = f2bf(v.z * f);
        tile[(dl4 + 3) * 72 + ml] = f2bf(v.w * f);
    }
    __syncthreads();
#pragma unroll
    for (int r = 0; r < 8; ++r) {
        int dl = r * 8 + (t >> 5);
        int d = d0 + dl;
        int ml = (t & 31) * 2;
        int e = ml >> 5, s = (ml >> 4) & 1, q = (ml >> 2) & 3, j = ml & 3;
        int pc = e * 32 + q * 8 + s * 4 + j;
        int phys = ((((pc >> 3) + d) & 7) << 3) | (pc & 7);
        unsigned int v0 = tile[dl * 72 + ml];
        unsigned int v1 = tile[dl * 72 + ml + 1];
        *(unsigned int*)(Vt + (size_t)d * M_KV + m0 + phys) = v0 | (v1 << 16);
    }
}

// ---------------------------------------------------------------------------
// Flash attention, software-pipelined:
//  - K DOUBLE-buffered LDS: K(it+1) DMA issued after mid barrier, drained at
//    next loop-top barrier -> overlapped with PV.
//  - Vt single-buffered: Vt(it) DMA issued after loop-top barrier, drained
//    at mid barrier -> overlapped with QK+softmax.
//  - S^T = K.Q^T (16x16x32); P packed in-register; PV on 16x16x32 with
//    pc-permuted Vt. No online max; l reduced once in epilogue.
// LDS = 2*16 + 32 = 64 KB -> 2 blocks/CU.
// ---------------------------------------------------------------------------
__global__ __launch_bounds__(256, 2) void flash_kernel(
    const unsigned short* __restrict__ Qw, const unsigned short* __restrict__ Kw,
    const unsigned short* __restrict__ Vt, const unsigned long long* __restrict__ Mb,
    unsigned short* __restrict__ Opart, float* __restrict__ Lpart,
    int nsplit, int lgNs)
{
    __shared__ __align__(16) unsigned short k_lds[2][64 * 128];  // 2 x 16 KB
    __shared__ __align__(16) unsigned short vt_lds[256 * 64];    // 32 KB

    const int L = blockIdx.x + gridDim.x * blockIdx.y;
    const int ly = L & (nsplit - 1);
    const int lx = L >> lgNs;
    const int chunkLen = M_KV >> lgNs;
    const int mBeg = ly * chunkLen;
    const int tid = threadIdx.x;
    const int wave = tid >> 6, lane = tid & 63, n = lane & 15, quad = lane >> 4;
    const int qrow0 = lx * 128 + wave * 32;
    constexpr float SC = 0.08838834764831845f * 1.4426950408889634f; // scale*log2(e)

    // Q fragments (rotated layout: unit' = (unit + row) & 15)
    short8 qf[2][4];
#pragma unroll
    for (int qt = 0; qt < 2; ++qt)
#pragma unroll
        for (int db = 0; db < 4; ++db) {
            int row = qrow0 + qt * 16 + n;
            int phys = (db * 4 + quad + row) & 15;
            qf[qt][db] = *(const short8*)(Qw + (size_t)row * DMID + phys * 8);
        }

    floatx4 Oacc[2][16];
#pragma unroll
    for (int qt = 0; qt < 2; ++qt)
#pragma unroll
        for (int dt = 0; dt < 16; ++dt) Oacc[qt][dt] = floatx4{0.f, 0.f, 0.f, 0.f};

    float lrow[2] = {0.f, 0.f};

    // staging invariants
    const unsigned short* kg = Kw + (size_t)(wave * 4 + (lane >> 4)) * DMID + (lane & 15) * 8;
    const unsigned short* vg = Vt + (size_t)(wave * 8 + (lane >> 3)) * M_KV + (lane & 7) * 8;
    unsigned short* vld = &vt_lds[wave * 512];
    const int kqn = quad + n;

    // prologue: K(0) DMA into buffer 0
#pragma unroll
    for (int r = 0; r < 4; ++r)
        gl_lds16(kg + (size_t)(mBeg + r * 16) * DMID, &k_lds[0][wave * 512 + r * 2048]);

    const int iters = chunkLen / 64;
    for (int it = 0; it < iters; ++it) {
        const int m0 = mBeg + it * 64;
        const unsigned short* kbuf = k_lds[it & 1];

        __syncthreads();   // drains K(it) DMA; separates PV(it-1) reads from Vt(it) writes

        // Vt(it) DMA (drained at mid barrier; overlaps QK+softmax)
#pragma unroll
        for (int r = 0; r < 8; ++r)
            gl_lds16(vg + (size_t)(r * 32) * M_KV + m0, vld + r * 2048);

        // mask words
        unsigned long long wbits[2];
#pragma unroll
        for (int qt = 0; qt < 2; ++qt)
            wbits[qt] = Mb[(size_t)(qrow0 + qt * 16 + n) * MWORDS + (m0 >> 6)];

        // ---- S^T = K Q^T (kv = 16kvt + 4quad + reg, q = n) ----
        floatx4 ST[4][2];
#pragma unroll
        for (int kvt = 0; kvt < 4; ++kvt) {
            const int rowoff = (kvt * 16 + n) * DMID;
            short8 a0 = *(const short8*)&kbuf[rowoff + (((kqn + 0) & 15) << 3)];
            short8 a1 = *(const short8*)&kbuf[rowoff + (((kqn + 4) & 15) << 3)];
            short8 a2 = *(const short8*)&kbuf[rowoff + (((kqn + 8) & 15) << 3)];
            short8 a3 = *(const short8*)&kbuf[rowoff + (((kqn + 12) & 15) << 3)];
#pragma unroll
            for (int qt = 0; qt < 2; ++qt) {
                floatx4 s = floatx4{0.f, 0.f, 0.f, 0.f};
                s = MFMA32K(a0, qf[qt][0], s);
                s = MFMA32K(a1, qf[qt][1], s);
                s = MFMA32K(a2, qf[qt][2], s);
                s = MFMA32K(a3, qf[qt][3], s);
                ST[kvt][qt] = s;
            }
        }

        // ---- p = exp2(s*SC), 0 where masked; pack to A-frags ----
        short8 pf8[2][2];
#pragma unroll
        for (int qt = 0; qt < 2; ++qt) {
            unsigned long long x = wbits[qt] >> (quad * 4);
            float lacc = 0.f;
#pragma unroll
            for (int kvt = 0; kvt < 4; ++kvt) {
                int e = kvt >> 1, s = kvt & 1;
                float p[4];
#pragma unroll
                for (int j = 0; j < 4; ++j) {
                    float v = __builtin_amdgcn_exp2f(ST[kvt][qt][j] * SC);
                    p[j] = ((x >> (kvt * 16 + j)) & 1ull) ? 0.f : v;
                    lacc += p[j];
                }
                __hip_bfloat162 h0 = __float22bfloat162_rn(make_float2(p[0], p[1]));
                __hip_bfloat162 h1 = __float22bfloat162_rn(make_float2(p[2], p[3]));
                unsigned u0, u1;
                __builtin_memcpy(&u0, &h0, 4);
                __builtin_memcpy(&u1, &h1, 4);
                ((unsigned*)&pf8[qt][e])[s * 2 + 0] = u0;
                ((unsigned*)&pf8[qt][e])[s * 2 + 1] = u1;
            }
            lrow[qt] += lacc;
        }

        __syncthreads();   // drains Vt(it) DMA; separates QK reads from K(it+1) writes

        // K(it+1) DMA into other buffer (drained at next loop-top barrier)
        if (it + 1 < iters) {
            unsigned short* knext = (unsigned short*)&k_lds[(it + 1) & 1][wave * 512];
#pragma unroll
            for (int r = 0; r < 4; ++r)
                gl_lds16(kg + (size_t)(m0 + 64 + r * 16) * DMID, knext + r * 2048);
        }

        // ---- O += P V (rotated contiguous b128 from vt_lds) ----
#pragma unroll
        for (int e = 0; e < 2; ++e) {
#pragma unroll
            for (int dt = 0; dt < 16; ++dt) {
                const int vb = (dt * 16 + n) * 64 + (((e * 4 + quad + n) & 7) << 3);
                short8 bv = *(const short8*)&vt_lds[vb];
                Oacc[0][dt] = MFMA32K(pf8[0][e], bv, Oacc[0][dt]);
                Oacc[1][dt] = MFMA32K(pf8[1][e], bv, Oacc[1][dt]);
            }
        }
    }

    // ---- epilogue: bf16 partials + cross-quad l reduction ----
    const size_t obase = (size_t)ly * N_Q * DV;
#pragma unroll
    for (int qt = 0; qt < 2; ++qt)
#pragma unroll
        for (int dt = 0; dt < 16; ++dt)
#pragma unroll
            for (int reg = 0; reg < 4; ++reg) {
                int gr = qrow0 + qt * 16 + quad * 4 + reg;
                Opart[obase + (size_t)gr * DV + dt * 16 + n] = f2bf(Oacc[qt][dt][reg]);
            }
#pragma unroll
    for (int qt = 0; qt < 2; ++qt) {
        float r = lrow[qt];
        r += __shfl_xor(r, 16);
        r += __shfl_xor(r, 32);
        if (quad == 0)
            Lpart[ly * N_Q + qrow0 + qt * 16 + n] = r;
    }
}

// ---------------------------------------------------------------------------
// Combine: out = (sum_c O_c) / (sum_c l_c).
// ---------------------------------------------------------------------------
__global__ __launch_bounds__(256) void combine_kernel(
    const unsigned short* __restrict__ Opart, const float* __restrict__ Lpart,
    float* __restrict__ out, int nsplit)
{
    const int row = blockIdx.x, d = threadIdx.x;
    float L = 0.f, o = 0.f;
    for (int c = 0; c < nsplit; ++c) {
        L += Lpart[c * N_Q + row];
        unsigned int b = Opart[((size_t)c * N_Q + row) * DV + d];
        o += __uint_as_float(b << 16);
    }
    out[(size_t)row * DV + d] = o / L;
}

// ---------------------------------------------------------------------------
extern "C" void kernel_launch(void* const* d_in, const int* in_sizes, int n_in,
                              void* d_out, int out_size, void* d_ws, size_t ws_size,
                              hipStream_t stream)
{
    const float* main_feat  = (const float*)d_in[0];
    const float* other_feat = (const float*)d_in[1];
    const float* fix_feat   = (const float*)d_in[2];
    const void*  mask       = d_in[3];
    const float* Wq         = (const float*)d_in[4];
    const float* bq         = (const float*)d_in[5];
    const float* Wk         = (const float*)d_in[6];
    const float* bk         = (const float*)d_in[7];
    float* out = (float*)d_out;

    char* ws = (char*)d_ws;
    unsigned short* Qw = (unsigned short*)(ws);                         // 2 MB
    unsigned short* Kw = (unsigned short*)(ws + (1ull << 21));          // 2 MB
    unsigned short* Vt = (unsigned short*)(ws + (2ull << 21));          // 4 MB
    int* flag = (int*)(ws + (8ull << 20));
    unsigned long long* Mb = (unsigned long long*)(ws + (8ull << 20) + 1024);  // 8 MB
    float* Lpart = (float*)(ws + (16ull << 20) + 2048);

    const size_t base = (16ull << 20) + 2048;
    auto need = [&](int ns) {
        return base + (size_t)ns * N_Q * 4 + (size_t)ns * N_Q * DV * 2;
    };
    int nsplit = 1, lgNs = 0;
    if (ws_size >= need(8))      { nsplit = 8; lgNs = 3; }
    else if (ws_size >= need(4)) { nsplit = 4; lgNs = 2; }
    else if (ws_size >= need(2)) { nsplit = 2; lgNs = 1; }

    unsigned short* Opart = (unsigned short*)(Lpart + (size_t)nsplit * N_Q);

    hipLaunchKernelGGL(detect_mask_kernel, dim3(1), dim3(64), 0, stream,
                       (const unsigned int*)mask, flag);
    hipLaunchKernelGGL(pack_mask_kernel, dim3(N_Q * MWORDS / 256), dim3(256), 0, stream,
                       mask, flag, Mb);
    hipLaunchKernelGGL(proj_kernel, dim3(128, 2), dim3(256), 0, stream,
                       main_feat, Wq, bq, other_feat, Wk, bk, Qw, Kw);
    hipLaunchKernelGGL(build_vt_kernel, dim3(128, 4), dim3(256), 0, stream,
                       other_feat, fix_feat, Vt);
    hipLaunchKernelGGL(flash_kernel, dim3(64, nsplit), dim3(256), 0, stream,
                       Qw, Kw, Vt, Mb, Opart, Lpart, nsplit, lgNs);
    hipLaunchKernelGGL(combine_kernel, dim3(N_Q), dim3(256), 0, stream,
                       Opart, Lpart, out, nsplit);
}